// Round 2
// baseline (1361.772 us; speedup 1.0000x reference)
//
#include <hip/hip_runtime.h>
#include <math.h>

#define B_   16
#define C_   32
#define N_   2048
#define K_   24
#define BNK_ (B_*N_*K_)      /* 786432 */

/* ws layout (float/int32 units) */
#define WS_XT   0u           /* xt[b][n][c]  : 1048576 f           */
#define WS_XXD  1048576u     /* xx[b][n]     : 32768 DOUBLES (64Ki f) */
#define WS_IDX  1114112u     /* idx[b][n][k] : 786432 i            */
#define WS_D2   1900544u     /* d2 [b][n][k] : 786432 f            */
#define WS_ATT  2686976u     /* att[b][n][k] : 786432 f            */
#define WS_ST   3473408u     /* sum/sumsq    : 128 f               */
#define WS_AB   3473536u     /* BN A,B       : 128 f               */

/* ---------------- K0: transpose x -> xt, fp64 row norms, zero stats ------- */
__global__ __launch_bounds__(256) void k0_prep(const float* __restrict__ x,
                                               float* __restrict__ ws) {
  int t = blockIdx.x * 256 + threadIdx.x;     /* 0..32767 = b*2048+n */
  int b = t >> 11, n = t & 2047;
  const float* xp = x + ((size_t)b * C_ * N_) + n;
  float* xt = ws + WS_XT + (size_t)t * C_;
  double s = 0.0;
#pragma unroll
  for (int c = 0; c < C_; ++c) {
    float v = xp[(size_t)c * N_];
    xt[c] = v;
    s = fma((double)v, (double)v, s);   /* exact products, fp64 accum */
  }
  ((double*)(ws + WS_XXD))[t] = s;
  if (t < 128) ws[WS_ST + t] = 0.f;
}

/* ---------------- K1: exact top-24 neighbors per (b,n) -------------------- */
/* Scores in fp64 (products of fp32 are exact in fp64) so the selected SET
   matches the mathematically exact top-k — immune to fp32 boundary ties.
   The 11-bit m-index is packed into the low mantissa bits of the score
   (2^-41 relative perturbation, ordering-safe), making each list entry a
   single self-indexing double: 24 doubles/lane in VGPRs, 51.2 KB LDS for
   the 4-quarter merge. */
__global__ __launch_bounds__(256) void k1_topk(float* __restrict__ ws) {
  __shared__ double pv[4][64][25];
  const float* xt = ws + WS_XT;
  const double* xxd = (const double*)(ws + WS_XXD);
  const int lane = threadIdx.x & 63;
  const int wv   = __builtin_amdgcn_readfirstlane(threadIdx.x >> 6);
  const int g = blockIdx.x;          /* 0..511 */
  const int b = g >> 5;
  const int n = ((g & 31) << 6) + lane;
  const int bn = (b << 11) + n;

  double xnd[C_];
  {
    const float* p = xt + (size_t)bn * C_;
#pragma unroll
    for (int c = 0; c < C_; ++c) xnd[c] = (double)p[c];
  }

  double val[K_];
#pragma unroll
  for (int j = 0; j < K_; ++j) val[j] = -1.7e308;

  const float* mrow = xt + ((size_t)((b << 11) + (wv << 9))) * C_;  /* uniform */
  const double* xxm = xxd + (b << 11) + (wv << 9);

  for (int mm = 0; mm < 512; ++mm) {
    const float* r = mrow + (size_t)mm * C_;   /* wave-uniform -> s_load */
    double a0 = 0.0, a1 = 0.0;
#pragma unroll
    for (int c = 0; c < 16; ++c) {
      a0 = fma((double)r[c],      xnd[c],      a0);
      a1 = fma((double)r[c + 16], xnd[c + 16], a1);
    }
    double s = 2.0 * (a0 + a1) - xxm[mm];
    long long bits = __double_as_longlong(s);
    bits = (bits & 0xFFFFFFFFFFFFF800ll) | (long long)((wv << 9) + mm);
    double sp = __longlong_as_double(bits);
    if (sp > val[K_ - 1]) {          /* branchless shift-insert */
      bool c2 = true;
#pragma unroll
      for (int j = K_ - 1; j >= 1; --j) {
        bool c1 = sp > val[j - 1];
        val[j] = c1 ? val[j - 1] : (c2 ? sp : val[j]);
        c2 = c1;
      }
      if (c2) val[0] = sp;
    }
  }
#pragma unroll
  for (int j = 0; j < K_; ++j) pv[wv][lane][j] = val[j];
  pv[wv][lane][K_] = -1.7e308;   /* sentinel */
  __syncthreads();
  if (wv == 0) {                    /* 4-way merge of sorted quarter lists */
    int i0 = 0, i1 = 0, i2 = 0, i3 = 0;
    double v0 = pv[0][lane][0], v1 = pv[1][lane][0], v2 = pv[2][lane][0], v3 = pv[3][lane][0];
    int*   op = (int*)ws + WS_IDX + (size_t)bn * K_;
    float* dp = ws + WS_D2 + (size_t)bn * K_;
    const double xxn = xxd[bn];
#pragma unroll 1
    for (int rr = 0; rr < K_; ++rr) {
      double bv = v0; int bq = 0;
      if (v1 > bv) { bv = v1; bq = 1; }
      if (v2 > bv) { bv = v2; bq = 2; }
      if (v3 > bv) { bv = v3; bq = 3; }
      op[rr] = (int)(__double_as_longlong(bv) & 0x7FFll);
      dp[rr] = (float)(xxn - bv);      /* d2 = ||xn||^2 + ||xm||^2 - 2 dot */
      if      (bq == 0) { ++i0; v0 = pv[0][lane][i0]; }
      else if (bq == 1) { ++i1; v1 = pv[1][lane][i1]; }
      else if (bq == 2) { ++i2; v2 = pv[2][lane][i2]; }
      else              { ++i3; v3 = pv[3][lane][i3]; }
    }
  }
}

/* ---------------- K2: attention MLP + softmax + BN stats ------------------ */
__global__ __launch_bounds__(256) void k2_att(const float* __restrict__ w1,
                                              const float* __restrict__ w2,
                                              const float* __restrict__ updw,
                                              float* __restrict__ ws) {
  __shared__ float ls[128];
  const int lane = threadIdx.x & 63;
  if (threadIdx.x < 128) ls[threadIdx.x] = 0.f;
  __syncthreads();
  const int w = blockIdx.x * 4 + (threadIdx.x >> 6);
  const float* xt = ws + WS_XT;

  float w1row[80];
#pragma unroll
  for (int f = 0; f < 80; ++f) w1row[f] = w1[lane * 80 + f];
  const float w2j = w2[lane];
  float updrow[C_];
#pragma unroll
  for (int c = 0; c < C_; ++c) updrow[c] = updw[lane * C_ + c];

  float s1 = 0.f, s2 = 0.f;

  for (int i = 0; i < 8; ++i) {
    const int bn = __builtin_amdgcn_readfirstlane(w * 8 + i);
    const int b  = bn >> 11;
    const int* ip   = (const int*)ws + WS_IDX + (size_t)bn * K_;
    const float* dp = ws + WS_D2 + (size_t)bn * K_;

    /* RBF: 24*16 = 384 entries distributed over 64 lanes x 6 slots */
    float arbf[6];
#pragma unroll
    for (int sl = 0; sl < 6; ++sl) {
      int e = sl * 64 + lane;
      int k = e >> 4, r = e & 15;
      float d2 = dp[k];
      float dist = sqrtf(fmaxf(d2, 1e-12f));
      float t = dist - (float)r * (5.0f / 15.0f);
      float rb = __expf(-10.f * t * t);
      arbf[sl] = fminf(fmaxf(rb, 1e-10f), 1.0f);
    }

    /* k-invariant cent contribution */
    const float* cw = xt + (size_t)bn * C_;
    float base = 0.f;
#pragma unroll
    for (int c = 0; c < C_; ++c) base = fmaf(cw[c], w1row[c], base);

    float lg[K_];
#pragma unroll
    for (int k = 0; k < K_; ++k) {
      const int mk = __builtin_amdgcn_readfirstlane(ip[k]);
      const float* nr = xt + ((size_t)((b << 11) + mk)) * C_;   /* uniform */
      float acc = base;
#pragma unroll
      for (int c = 0; c < C_; ++c) acc = fmaf(nr[c], w1row[32 + c], acc);
#pragma unroll
      for (int r = 0; r < 16; ++r) {
        const int e = k * 16 + r;
        float rb = __int_as_float(
            __builtin_amdgcn_readlane(__float_as_int(arbf[e >> 6]), e & 63));
        acc = fmaf(rb, w1row[64 + r], acc);
      }
      float h = acc > 0.f ? acc : 0.2f * acc;   /* leaky 0.2 */
      float t = h * w2j;
#pragma unroll
      for (int d = 1; d < 64; d <<= 1) t += __shfl_xor(t, d, 64);
      lg[k] = t;                                /* all lanes hold logit_k */
    }
    /* softmax over K */
    float mx = lg[0];
#pragma unroll
    for (int k = 1; k < K_; ++k) mx = fmaxf(mx, lg[k]);
    float den = 0.f;
#pragma unroll
    for (int k = 0; k < K_; ++k) { lg[k] = __expf(lg[k] - mx); den += lg[k]; }
    const float inv = 1.f / den;
#pragma unroll
    for (int k = 0; k < K_; ++k) lg[k] *= inv;

    if (lane == 0) {
      float* ap = ws + WS_ATT + (size_t)bn * K_;
#pragma unroll
      for (int k = 0; k < K_; ++k) ap[k] = lg[k];
    }
    /* BN stats: upd[k][j] = att_k * (neigh_k . updw_row_j) */
#pragma unroll
    for (int k = 0; k < K_; ++k) {
      const int mk = __builtin_amdgcn_readfirstlane(ip[k]);
      const float* nr = xt + ((size_t)((b << 11) + mk)) * C_;
      float na = 0.f;
#pragma unroll
      for (int c = 0; c < C_; ++c) na = fmaf(nr[c], updrow[c], na);
      float u = lg[k] * na;
      s1 += u;
      s2 = fmaf(u, u, s2);
    }
  }
  atomicAdd(&ls[lane], s1);
  atomicAdd(&ls[64 + lane], s2);
  __syncthreads();
  if (threadIdx.x < 128) atomicAdd(ws + WS_ST + threadIdx.x, ls[threadIdx.x]);
}

/* ---------------- K3: finalize BN scale/shift ----------------------------- */
__global__ void k3_bn(const float* __restrict__ gam, const float* __restrict__ bet,
                      float* __restrict__ ws) {
  const int o = threadIdx.x;   /* 64 */
  float s1 = ws[WS_ST + o], s2 = ws[WS_ST + 64 + o];
  const float cnt = (float)BNK_;
  float mean = s1 / cnt;
  float var = fmaxf(s2 / cnt - mean * mean, 0.f);
  float A = gam[o] / sqrtf(var + 1e-5f);
  ws[WS_AB + o] = A;
  ws[WS_AB + 64 + o] = bet[o] - mean * A;
}

/* ---------------- K4: normalize + activation + residual + mean_k + store -- */
__global__ __launch_bounds__(256) void k4_out(const float* __restrict__ updw,
                                              const float* __restrict__ resw,
                                              float* __restrict__ out,
                                              const float* __restrict__ ws) {
  const int lane = threadIdx.x & 63;     /* = output channel o */
  const int w = blockIdx.x * 4 + (threadIdx.x >> 6);
  const float* xt = ws + WS_XT;
  float updrow[C_], resrow[C_];
#pragma unroll
  for (int c = 0; c < C_; ++c) {
    updrow[c] = updw[lane * C_ + c];
    resrow[c] = resw[lane * C_ + c];
  }
  const float Aj = ws[WS_AB + lane];
  const float Bj = ws[WS_AB + 64 + lane];
  for (int i = 0; i < 8; ++i) {
    const int bn = __builtin_amdgcn_readfirstlane(w * 8 + i);
    const int b = bn >> 11, n = bn & 2047;
    const int* ip   = (const int*)ws + WS_IDX + (size_t)bn * K_;
    const float* ap = ws + WS_ATT + (size_t)bn * K_;
    float facc = 0.f, racc = 0.f;
#pragma unroll
    for (int k = 0; k < K_; ++k) {
      const int mk = __builtin_amdgcn_readfirstlane(ip[k]);
      const float* nr = xt + ((size_t)((b << 11) + mk)) * C_;   /* uniform */
      float na = 0.f, ra = 0.f;
#pragma unroll
      for (int c = 0; c < C_; ++c) {
        na = fmaf(nr[c], updrow[c], na);
        ra = fmaf(nr[c], resrow[c], ra);
      }
      float u = ap[k] * na;
      float v = fmaf(u, Aj, Bj);
      v = v > 0.f ? v : 0.02f * v;    /* leaky 0.02 */
      facc += v;
      racc += ra;
    }
    out[((size_t)(b * 64 + lane)) * N_ + n] = (facc + 0.1f * racc) * (1.f / 24.f);
  }
}

extern "C" void kernel_launch(void* const* d_in, const int* in_sizes, int n_in,
                              void* d_out, int out_size, void* d_ws, size_t ws_size,
                              hipStream_t stream) {
  (void)in_sizes; (void)n_in; (void)out_size; (void)ws_size;
  const float* x    = (const float*)d_in[0];
  /* d_in[1] = idx_base (unused by reference) */
  const float* w1   = (const float*)d_in[2];
  const float* w2   = (const float*)d_in[3];
  const float* updw = (const float*)d_in[4];
  const float* bng  = (const float*)d_in[5];
  const float* bnb  = (const float*)d_in[6];
  const float* resw = (const float*)d_in[7];
  float* out = (float*)d_out;
  float* ws  = (float*)d_ws;

  k0_prep<<<dim3(128),  dim3(256), 0, stream>>>(x, ws);
  k1_topk<<<dim3(512),  dim3(256), 0, stream>>>(ws);
  k2_att <<<dim3(1024), dim3(256), 0, stream>>>(w1, w2, updw, ws);
  k3_bn  <<<dim3(1),    dim3(64),  0, stream>>>(bng, bnb, ws);
  k4_out <<<dim3(1024), dim3(256), 0, stream>>>(updw, resw, out, ws);
}

// Round 3
// 946.841 us; speedup vs baseline: 1.4382x; 1.4382x over previous
//
#include <hip/hip_runtime.h>
#include <math.h>

#define B_   16
#define C_   32
#define N_   2048
#define K_   24
#define BNK_ (B_*N_*K_)      /* 786432 */

/* ws layout (float/int32 units) */
#define WS_XT   0u           /* xt[b][n][c]  : 1048576 f           */
#define WS_XXD  1048576u     /* xx[b][n]     : 32768 DOUBLES (64Ki f) */
#define WS_IDX  1114112u     /* idx[b][n][k] : 786432 i            */
#define WS_D2   1900544u     /* d2 [b][n][k] : 786432 f            */
#define WS_ATT  2686976u     /* att[b][n][k] : 786432 f            */
#define WS_ST   3473408u     /* sum/sumsq    : 128 f               */
#define WS_AB   3473536u     /* BN A,B       : 128 f               */

/* ---------------- K0: transpose x -> xt, fp64 row norms, zero stats ------- */
__global__ __launch_bounds__(256) void k0_prep(const float* __restrict__ x,
                                               float* __restrict__ ws) {
  int t = blockIdx.x * 256 + threadIdx.x;     /* 0..32767 = b*2048+n */
  int b = t >> 11, n = t & 2047;
  const float* xp = x + ((size_t)b * C_ * N_) + n;
  float* xt = ws + WS_XT + (size_t)t * C_;
  double s = 0.0;
#pragma unroll
  for (int c = 0; c < C_; ++c) {
    float v = xp[(size_t)c * N_];
    xt[c] = v;
    s = fma((double)v, (double)v, s);
  }
  ((double*)(ws + WS_XXD))[t] = s;
  if (t < 128) ws[WS_ST + t] = 0.f;
}

/* ---------------- K1: exact top-24 neighbors per (b,n) -------------------- */
__global__ __launch_bounds__(256) void k1_topk(float* __restrict__ ws) {
  __shared__ double pv[4][64][25];
  const float* xt = ws + WS_XT;
  const double* xxd = (const double*)(ws + WS_XXD);
  const int lane = threadIdx.x & 63;
  const int wv   = __builtin_amdgcn_readfirstlane(threadIdx.x >> 6);
  const int g = blockIdx.x;          /* 0..511 */
  const int b = g >> 5;
  const int n = ((g & 31) << 6) + lane;
  const int bn = (b << 11) + n;

  double xnd[C_];
  {
    const float* p = xt + (size_t)bn * C_;
#pragma unroll
    for (int c = 0; c < C_; ++c) xnd[c] = (double)p[c];
  }

  double val[K_];
#pragma unroll
  for (int j = 0; j < K_; ++j) val[j] = -1.7e308;

  const float* mrow = xt + ((size_t)((b << 11) + (wv << 9))) * C_;  /* uniform */
  const double* xxm = xxd + (b << 11) + (wv << 9);

  for (int mm = 0; mm < 512; ++mm) {
    const float* r = mrow + (size_t)mm * C_;   /* wave-uniform -> s_load */
    double a0 = 0.0, a1 = 0.0;
#pragma unroll
    for (int c = 0; c < 16; ++c) {
      a0 = fma((double)r[c],      xnd[c],      a0);
      a1 = fma((double)r[c + 16], xnd[c + 16], a1);
    }
    double s = 2.0 * (a0 + a1) - xxm[mm];
    long long bits = __double_as_longlong(s);
    bits = (bits & 0xFFFFFFFFFFFFF800ll) | (long long)((wv << 9) + mm);
    double sp = __longlong_as_double(bits);
    if (sp > val[K_ - 1]) {          /* branchless shift-insert */
      bool c2 = true;
#pragma unroll
      for (int j = K_ - 1; j >= 1; --j) {
        bool c1 = sp > val[j - 1];
        val[j] = c1 ? val[j - 1] : (c2 ? sp : val[j]);
        c2 = c1;
      }
      if (c2) val[0] = sp;
    }
  }
#pragma unroll
  for (int j = 0; j < K_; ++j) pv[wv][lane][j] = val[j];
  pv[wv][lane][K_] = -1.7e308;   /* sentinel */
  __syncthreads();
  if (wv == 0) {                    /* 4-way merge of sorted quarter lists */
    int i0 = 0, i1 = 0, i2 = 0, i3 = 0;
    double v0 = pv[0][lane][0], v1 = pv[1][lane][0], v2 = pv[2][lane][0], v3 = pv[3][lane][0];
    int*   op = (int*)ws + WS_IDX + (size_t)bn * K_;
    float* dp = ws + WS_D2 + (size_t)bn * K_;
    const double xxn = xxd[bn];
#pragma unroll 1
    for (int rr = 0; rr < K_; ++rr) {
      double bv = v0; int bq = 0;
      if (v1 > bv) { bv = v1; bq = 1; }
      if (v2 > bv) { bv = v2; bq = 2; }
      if (v3 > bv) { bv = v3; bq = 3; }
      op[rr] = (int)(__double_as_longlong(bv) & 0x7FFll);
      dp[rr] = (float)(xxn - bv);      /* d2 = ||xn||^2 + ||xm||^2 - 2 dot */
      if      (bq == 0) { ++i0; v0 = pv[0][lane][i0]; }
      else if (bq == 1) { ++i1; v1 = pv[1][lane][i1]; }
      else if (bq == 2) { ++i2; v2 = pv[2][lane][i2]; }
      else              { ++i3; v3 = pv[3][lane][i3]; }
    }
  }
}

/* ---------------- K2a: attention MLP + softmax (lane = point) ------------- */
/* Each lane owns one (b,n). 4 waves split k: wave wv handles k in [6wv,6wv+6).
   Neighbor rows are per-lane float4 gathers (deep ILP, no cross-lane ops,
   no data-dependent scalar-load chains). W1/W2 are wave-uniform -> s_load.
   Softmax via one LDS exchange per block. */
__global__ __launch_bounds__(256) void k2a_att(const float* __restrict__ w1,
                                               const float* __restrict__ w2,
                                               float* __restrict__ ws) {
  __shared__ float lgs[64][25];
  const int lane = threadIdx.x & 63;
  const int wv   = threadIdx.x >> 6;
  const int bn   = blockIdx.x * 64 + lane;
  const int b    = bn >> 11;
  const float* xt = ws + WS_XT;

  /* prefetch this lane's 6 neighbor indices + d2 */
  int   mk[6];
  float dd[6];
  {
    const int*   ip = (const int*)ws + WS_IDX + (size_t)bn * K_;
    const float* dp = ws + WS_D2 + (size_t)bn * K_;
#pragma unroll
    for (int kk = 0; kk < 6; ++kk) { mk[kk] = ip[wv * 6 + kk]; dd[kk] = dp[wv * 6 + kk]; }
  }

  /* cent row (per-lane, vectorized) */
  float cent[C_];
  {
    const float4* cp = (const float4*)(xt + (size_t)bn * C_);
#pragma unroll
    for (int q = 0; q < 8; ++q) {
      float4 v = cp[q];
      cent[4 * q] = v.x; cent[4 * q + 1] = v.y; cent[4 * q + 2] = v.z; cent[4 * q + 3] = v.w;
    }
  }

  /* base[o] = cent . w1[o][0:32] — w1 wave-uniform scalar operands */
  float base[64];
#pragma unroll 4
  for (int o = 0; o < 64; ++o) {
    float a = 0.f;
#pragma unroll
    for (int c = 0; c < C_; ++c) a = fmaf(cent[c], w1[o * 80 + c], a);
    base[o] = a;
  }

#pragma unroll 1
  for (int kk = 0; kk < 6; ++kk) {
    float neigh[C_];
    {
      const float4* np = (const float4*)(xt + ((size_t)((b << 11) + mk[kk])) * C_);
#pragma unroll
      for (int q = 0; q < 8; ++q) {
        float4 v = np[q];
        neigh[4 * q] = v.x; neigh[4 * q + 1] = v.y; neigh[4 * q + 2] = v.z; neigh[4 * q + 3] = v.w;
      }
    }
    float dist = sqrtf(fmaxf(dd[kk], 1e-12f));
    float rbf[16];
#pragma unroll
    for (int r = 0; r < 16; ++r) {
      float t = dist - (float)r * (5.0f / 15.0f);
      float e = __expf(-10.f * t * t);
      rbf[r] = fminf(fmaxf(e, 1e-10f), 1.0f);
    }
    float lg = 0.f;
#pragma unroll 2
    for (int o = 0; o < 64; ++o) {
      float acc = base[o];
#pragma unroll
      for (int c = 0; c < C_; ++c) acc = fmaf(neigh[c], w1[o * 80 + 32 + c], acc);
#pragma unroll
      for (int r = 0; r < 16; ++r)  acc = fmaf(rbf[r], w1[o * 80 + 64 + r], acc);
      float h = acc > 0.f ? acc : 0.2f * acc;   /* leaky 0.2 */
      lg = fmaf(h, w2[o], lg);
    }
    lgs[lane][wv * 6 + kk] = lg;
  }
  __syncthreads();
  if (wv == 0) {                       /* softmax over 24 k per point */
    float l[K_];
#pragma unroll
    for (int k = 0; k < K_; ++k) l[k] = lgs[lane][k];
    float mx = l[0];
#pragma unroll
    for (int k = 1; k < K_; ++k) mx = fmaxf(mx, l[k]);
    float den = 0.f;
#pragma unroll
    for (int k = 0; k < K_; ++k) { l[k] = __expf(l[k] - mx); den += l[k]; }
    const float inv = 1.f / den;
    float* ap = ws + WS_ATT + (size_t)bn * K_;
#pragma unroll
    for (int k = 0; k < K_; ++k) ap[k] = l[k] * inv;
  }
}

/* ---------------- K2b: BN statistics (lane = channel j) ------------------- */
__global__ __launch_bounds__(256) void k2b_stats(const float* __restrict__ updw,
                                                 float* __restrict__ ws) {
  __shared__ float ls[128];
  const int lane = threadIdx.x & 63;
  if (threadIdx.x < 128) ls[threadIdx.x] = 0.f;
  __syncthreads();
  const int w = blockIdx.x * 4 + (threadIdx.x >> 6);
  const float* xt = ws + WS_XT;
  float updrow[C_];
#pragma unroll
  for (int c = 0; c < C_; ++c) updrow[c] = updw[lane * C_ + c];
  float s1 = 0.f, s2 = 0.f;
  for (int i = 0; i < 8; ++i) {
    const int bn = __builtin_amdgcn_readfirstlane(w * 8 + i);
    const int b  = bn >> 11;
    const int*   ip = (const int*)ws + WS_IDX + (size_t)bn * K_;
    const float* ap = ws + WS_ATT + (size_t)bn * K_;
#pragma unroll
    for (int k = 0; k < K_; ++k) {
      const int mk = __builtin_amdgcn_readfirstlane(ip[k]);
      const float* nr = xt + ((size_t)((b << 11) + mk)) * C_;   /* uniform */
      float na = 0.f;
#pragma unroll
      for (int c = 0; c < C_; ++c) na = fmaf(nr[c], updrow[c], na);
      float u = ap[k] * na;
      s1 += u;
      s2 = fmaf(u, u, s2);
    }
  }
  atomicAdd(&ls[lane], s1);
  atomicAdd(&ls[64 + lane], s2);
  __syncthreads();
  if (threadIdx.x < 128) atomicAdd(ws + WS_ST + threadIdx.x, ls[threadIdx.x]);
}

/* ---------------- K3: finalize BN scale/shift ----------------------------- */
__global__ void k3_bn(const float* __restrict__ gam, const float* __restrict__ bet,
                      float* __restrict__ ws) {
  const int o = threadIdx.x;   /* 64 */
  float s1 = ws[WS_ST + o], s2 = ws[WS_ST + 64 + o];
  const float cnt = (float)BNK_;
  float mean = s1 / cnt;
  float var = fmaxf(s2 / cnt - mean * mean, 0.f);
  float A = gam[o] / sqrtf(var + 1e-5f);
  ws[WS_AB + o] = A;
  ws[WS_AB + 64 + o] = bet[o] - mean * A;
}

/* ---------------- K4: normalize + activation + residual + mean_k + store -- */
__global__ __launch_bounds__(256) void k4_out(const float* __restrict__ updw,
                                              const float* __restrict__ resw,
                                              float* __restrict__ out,
                                              const float* __restrict__ ws) {
  const int lane = threadIdx.x & 63;     /* = output channel o */
  const int w = blockIdx.x * 4 + (threadIdx.x >> 6);
  const float* xt = ws + WS_XT;
  float updrow[C_], resrow[C_];
#pragma unroll
  for (int c = 0; c < C_; ++c) {
    updrow[c] = updw[lane * C_ + c];
    resrow[c] = resw[lane * C_ + c];
  }
  const float Aj = ws[WS_AB + lane];
  const float Bj = ws[WS_AB + 64 + lane];
  for (int i = 0; i < 8; ++i) {
    const int bn = __builtin_amdgcn_readfirstlane(w * 8 + i);
    const int b = bn >> 11, n = bn & 2047;
    const int*   ip = (const int*)ws + WS_IDX + (size_t)bn * K_;
    const float* ap = ws + WS_ATT + (size_t)bn * K_;
    float facc = 0.f, racc = 0.f;
#pragma unroll
    for (int k = 0; k < K_; ++k) {
      const int mk = __builtin_amdgcn_readfirstlane(ip[k]);
      const float* nr = xt + ((size_t)((b << 11) + mk)) * C_;   /* uniform */
      float na = 0.f, ra = 0.f;
#pragma unroll
      for (int c = 0; c < C_; ++c) {
        na = fmaf(nr[c], updrow[c], na);
        ra = fmaf(nr[c], resrow[c], ra);
      }
      float u = ap[k] * na;
      float v = fmaf(u, Aj, Bj);
      v = v > 0.f ? v : 0.02f * v;    /* leaky 0.02 */
      facc += v;
      racc += ra;
    }
    out[((size_t)(b * 64 + lane)) * N_ + n] = (facc + 0.1f * racc) * (1.f / 24.f);
  }
}

extern "C" void kernel_launch(void* const* d_in, const int* in_sizes, int n_in,
                              void* d_out, int out_size, void* d_ws, size_t ws_size,
                              hipStream_t stream) {
  (void)in_sizes; (void)n_in; (void)out_size; (void)ws_size;
  const float* x    = (const float*)d_in[0];
  /* d_in[1] = idx_base (unused by reference) */
  const float* w1   = (const float*)d_in[2];
  const float* w2   = (const float*)d_in[3];
  const float* updw = (const float*)d_in[4];
  const float* bng  = (const float*)d_in[5];
  const float* bnb  = (const float*)d_in[6];
  const float* resw = (const float*)d_in[7];
  float* out = (float*)d_out;
  float* ws  = (float*)d_ws;

  k0_prep  <<<dim3(128),  dim3(256), 0, stream>>>(x, ws);
  k1_topk  <<<dim3(512),  dim3(256), 0, stream>>>(ws);
  k2a_att  <<<dim3(512),  dim3(256), 0, stream>>>(w1, w2, ws);
  k2b_stats<<<dim3(1024), dim3(256), 0, stream>>>(updw, ws);
  k3_bn    <<<dim3(1),    dim3(64),  0, stream>>>(bng, bnb, ws);
  k4_out   <<<dim3(1024), dim3(256), 0, stream>>>(updw, resw, out, ws);
}